// Round 3
// baseline (11727.911 us; speedup 1.0000x reference)
//
#include <hip/hip_runtime.h>
#include <cstdint>

typedef unsigned short ushort_t;
typedef __attribute__((ext_vector_type(8))) short short8;
typedef __attribute__((ext_vector_type(4))) float f32x4;
typedef unsigned long long u64;

#define T_STEPS 512
#define BATCH   64
#define IDIM    512
#define HIDDEN  1024
#define NWGP    32          // persistent workgroups
#define NC      32          // output columns per WG
#define BH      (BATCH*HIDDEN)   // 65536

__device__ __forceinline__ ushort_t f2bf(float f) {
  unsigned int x = __float_as_uint(f);
  unsigned int r = (x + 0x7fffu + ((x >> 16) & 1u)) >> 16;
  return (ushort_t)r;
}
__device__ __forceinline__ float sigmoid_f(float x) { return 1.f / (1.f + __expf(-x)); }
__device__ __forceinline__ float tanh_f(float x)    { return 1.f - 2.f / (1.f + __expf(2.f * x)); }

union S8U { short8 s; u64 u[2]; };

// coherent (LLC, sc1) 16B load as two 8B relaxed agent atomics
__device__ __forceinline__ short8 coh_load16(const u64* p) {
  S8U r;
  r.u[0] = __hip_atomic_load(p,     __ATOMIC_RELAXED, __HIP_MEMORY_SCOPE_AGENT);
  r.u[1] = __hip_atomic_load(p + 1, __ATOMIC_RELAXED, __HIP_MEMORY_SCOPE_AGENT);
  return r.s;
}

// single-poller barrier wait: 32 pollers total instead of 2048
__device__ __forceinline__ void poll_ctr(int* ctr, int target) {
  if (threadIdx.x == 0) {
    while (__hip_atomic_load(ctr, __ATOMIC_RELAXED, __HIP_MEMORY_SCOPE_AGENT) < target)
      __builtin_amdgcn_s_sleep(1);
  }
  __syncthreads();
}

// ---------------- weight conversion: f32 -> bf16, split h-part / x-part ----
__global__ __launch_bounds__(256) void convert_weights(
    const float* __restrict__ Wz, const float* __restrict__ Wh,
    ushort_t* __restrict__ Wzh, ushort_t* __restrict__ Wzx,
    ushort_t* __restrict__ Whh, ushort_t* __restrict__ Whx)
{
  int j = blockIdx.x;
  const float* W = blockIdx.y ? Wh : Wz;
  ushort_t* Bh = blockIdx.y ? Whh : Wzh;
  ushort_t* Bx = blockIdx.y ? Whx : Wzx;
  const float* row = W + (size_t)j * (HIDDEN + IDIM);
  for (int c = threadIdx.x; c < HIDDEN + IDIM; c += 256) {
    ushort_t v = f2bf(row[c]);
    if (c < HIDDEN) Bh[(size_t)j * HIDDEN + c] = v;
    else            Bx[(size_t)j * IDIM + (c - HIDDEN)] = v;
  }
}

// ---------------- phase 1: Gx = x @ Wx^T + b  (two GEMMs via blockIdx.z) ----
__global__ __launch_bounds__(256) void gx_gemm(
    const float* __restrict__ x,
    const ushort_t* __restrict__ Wzx, const ushort_t* __restrict__ Whx,
    const float* __restrict__ bz, const float* __restrict__ bh,
    float* __restrict__ outZ, float* __restrict__ outR)
{
  const int which = blockIdx.z;
  const ushort_t* W = which ? Whx : Wzx;
  const float* bias = which ? bh : bz;
  float* out = which ? outR : outZ;
  const int m0 = blockIdx.x * 64;
  const int n0 = blockIdx.y * 64;
  __shared__ ushort_t As[64 * 40];
  __shared__ ushort_t Bs[64 * 40];
  const int tid = threadIdx.x;
  const int lane = tid & 63, w4 = tid >> 6;
  const int row = tid >> 2, q = tid & 3;
  f32x4 acc[4] = {{0,0,0,0},{0,0,0,0},{0,0,0,0},{0,0,0,0}};
  for (int kk = 0; kk < IDIM; kk += 32) {
    const float* xs = &x[(size_t)(m0 + row) * IDIM + kk + q * 8];
    float4 f0 = *(const float4*)xs;
    float4 f1 = *(const float4*)(xs + 4);
    short8 av;
    av[0]=f2bf(f0.x); av[1]=f2bf(f0.y); av[2]=f2bf(f0.z); av[3]=f2bf(f0.w);
    av[4]=f2bf(f1.x); av[5]=f2bf(f1.y); av[6]=f2bf(f1.z); av[7]=f2bf(f1.w);
    short8 bv = *(const short8*)&W[(size_t)(n0 + row) * IDIM + kk + q * 8];
    __syncthreads();
    *(short8*)&As[row * 40 + q * 8] = av;
    *(short8*)&Bs[row * 40 + q * 8] = bv;
    __syncthreads();
    short8 af = *(const short8*)&As[(w4 * 16 + (lane & 15)) * 40 + (lane >> 4) * 8];
    #pragma unroll
    for (int c = 0; c < 4; ++c) {
      short8 bf = *(const short8*)&Bs[(c * 16 + (lane & 15)) * 40 + (lane >> 4) * 8];
      acc[c] = __builtin_amdgcn_mfma_f32_16x16x32_bf16(af, bf, acc[c], 0, 0, 0);
    }
  }
  #pragma unroll
  for (int c = 0; c < 4; ++c) {
    int j = n0 + c * 16 + (lane & 15);
    float bv = bias[j];
    #pragma unroll
    for (int r = 0; r < 4; ++r) {
      int m = m0 + w4 * 16 + (lane >> 4) * 4 + r;
      out[(size_t)m * HIDDEN + j] = acc[c][r] + bv;
    }
  }
}

// ---------------- persistent recurrent kernel (fence-free, sc1 comms) ------
// Release protocol: ONLY the 16B sc1 broadcast store sits before the
// vmcnt(0) drain; all bulk Z/R/H HBM stores are deferred until after the
// arrival fetch_add so they drain during the next poll+compute window.
__global__ __launch_bounds__(256) void gru_persist(
    const ushort_t* __restrict__ Wzh, const ushort_t* __restrict__ Whh,
    float* __restrict__ H, float* __restrict__ Z, float* __restrict__ R,
    u64* __restrict__ h_buf, u64* __restrict__ ghb, int* __restrict__ ctr)
{
  extern __shared__ ushort_t smem[];        // Wz slice [32][1024], Wh slice, scratch
  ushort_t* scr = smem + 65536;             // [64][48] bf16 transpose scratch
  const int w = blockIdx.x;
  const int tid = threadIdx.x;
  const int lane = tid & 63;
  const int wv = tid >> 6;                  // wave 0..3
  const int jbase = w * NC;

  // stage this WG's weight slices (XOR-swizzled rows: k ^= (row&7)<<3)
  for (int c = tid; c < NC * 128; c += 256) {
    int row = c >> 7, k8 = (c & 127) * 8;
    int dst = row * 1024 + (k8 ^ ((row & 7) << 3));
    *(short8*)&smem[dst]         = *(const short8*)&Wzh[(size_t)(jbase + row) * 1024 + k8];
    *(short8*)&smem[32768 + dst] = *(const short8*)&Whh[(size_t)(jbase + row) * 1024 + k8];
  }

  // writer-thread mapping (store layout): row = tid>>2, cols scc..scc+7
  const int srow = tid >> 2, scc = (tid & 3) * 8;
  u64* hwp = h_buf + srow * 256 + ((jbase + scc) >> 2);
  u64* gwp = ghb   + srow * 256 + ((jbase + scc) >> 2);

  // init: h0 = 0 (coherent) — only these block the first arrival
  __hip_atomic_store(hwp,     0ull, __ATOMIC_RELAXED, __HIP_MEMORY_SCOPE_AGENT);
  __hip_atomic_store(hwp + 1, 0ull, __ATOMIC_RELAXED, __HIP_MEMORY_SCOPE_AGENT);
  asm volatile("s_waitcnt vmcnt(0)" ::: "memory");
  __syncthreads();   // also covers LDS weight staging
  if (tid == 0) __hip_atomic_fetch_add(ctr, 1, __ATOMIC_RELAXED, __HIP_MEMORY_SCOPE_AGENT);
  {  // H[0] = 0 (bulk, post-arrival)
    float4 z4 = {0.f, 0.f, 0.f, 0.f};
    *(float4*)&H[(size_t)srow * 1024 + jbase + scc]     = z4;
    *(float4*)&H[(size_t)srow * 1024 + jbase + scc + 4] = z4;
  }

  // compute-thread constants
  const int koff = (lane >> 4) * 8;
  const int ar = wv * 16 + (lane & 15);     // A-fragment batch row
  const int abase = ar * 256;               // u64 index of that row
  const int lc = lane & 15;
  const int m0 = wv * 16 + (lane >> 4) * 4; // output batch rows m0..m0+3
  const int wb0 = lc * 1024,        wb1 = (16 + lc) * 1024;
  const int sz0 = (lc & 7) << 3,    sz1 = ((16 + lc) & 7) << 3;

  float hreg[2][4] = {{0.f,0.f,0.f,0.f},{0.f,0.f,0.f,0.f}};

  for (int t = 0; t < T_STEPS; ++t) {
    const size_t zoff = (size_t)t * BH;

    // prefetch Gxz (overlaps with poll)
    float gz[2][4];
    #pragma unroll
    for (int c = 0; c < 2; ++c)
      #pragma unroll
      for (int r = 0; r < 4; ++r)
        gz[c][r] = Z[zoff + (size_t)(m0 + r) * 1024 + jbase + c * 16 + lc];

    poll_ctr(ctr, NWGP * (2 * t + 1));

    // phase A: z-gate matvec over full h (coherent loads)
    f32x4 acc0 = {0,0,0,0}, acc1 = {0,0,0,0};
    #pragma unroll
    for (int kk = 0; kk < HIDDEN; kk += 32) {
      int k = kk + koff;
      short8 a  = coh_load16(h_buf + abase + (k >> 2));
      short8 b0 = *(const short8*)&smem[wb0 + (k ^ sz0)];
      short8 b1 = *(const short8*)&smem[wb1 + (k ^ sz1)];
      acc0 = __builtin_amdgcn_mfma_f32_16x16x32_bf16(a, b0, acc0, 0, 0, 0);
      acc1 = __builtin_amdgcn_mfma_f32_16x16x32_bf16(a, b1, acc1, 0, 0, 0);
    }
    float g[2][4];
    #pragma unroll
    for (int c = 0; c < 2; ++c)
      #pragma unroll
      for (int r = 0; r < 4; ++r) {
        float gv = sigmoid_f((c ? acc1[r] : acc0[r]) + gz[c][r]);
        g[c][r] = gv;
        scr[(m0 + r) * 48 + c * 16 + lc] = f2bf(gv * hreg[c][r]);
      }
    __syncthreads();
    { S8U v; v.s = *(const short8*)&scr[srow * 48 + scc];
      __hip_atomic_store(gwp,     v.u[0], __ATOMIC_RELAXED, __HIP_MEMORY_SCOPE_AGENT);
      __hip_atomic_store(gwp + 1, v.u[1], __ATOMIC_RELAXED, __HIP_MEMORY_SCOPE_AGENT); }
    asm volatile("s_waitcnt vmcnt(0)" ::: "memory");
    __syncthreads();
    if (tid == 0) __hip_atomic_fetch_add(ctr, 1, __ATOMIC_RELAXED, __HIP_MEMORY_SCOPE_AGENT);

    // bulk: Z = g (post-arrival, drains in background)
    #pragma unroll
    for (int c = 0; c < 2; ++c)
      #pragma unroll
      for (int r = 0; r < 4; ++r)
        Z[zoff + (size_t)(m0 + r) * 1024 + jbase + c * 16 + lc] = g[c][r];

    // prefetch Gxh (overlaps with poll)
    float gh[2][4];
    #pragma unroll
    for (int c = 0; c < 2; ++c)
      #pragma unroll
      for (int r = 0; r < 4; ++r)
        gh[c][r] = R[zoff + (size_t)(m0 + r) * 1024 + jbase + c * 16 + lc];

    poll_ctr(ctr, NWGP * (2 * t + 2));

    // phase B: candidate matvec over full g*h
    f32x4 acc2 = {0,0,0,0}, acc3 = {0,0,0,0};
    #pragma unroll
    for (int kk = 0; kk < HIDDEN; kk += 32) {
      int k = kk + koff;
      short8 a  = coh_load16(ghb + abase + (k >> 2));
      short8 b0 = *(const short8*)&smem[32768 + wb0 + (k ^ sz0)];
      short8 b1 = *(const short8*)&smem[32768 + wb1 + (k ^ sz1)];
      acc2 = __builtin_amdgcn_mfma_f32_16x16x32_bf16(a, b0, acc2, 0, 0, 0);
      acc3 = __builtin_amdgcn_mfma_f32_16x16x32_bf16(a, b1, acc3, 0, 0, 0);
    }
    float hn[2][4];
    #pragma unroll
    for (int c = 0; c < 2; ++c)
      #pragma unroll
      for (int r = 0; r < 4; ++r) {
        float cand = tanh_f((c ? acc3[r] : acc2[r]) + gh[c][r]);
        float v = (1.f - g[c][r]) * hreg[c][r] + g[c][r] * cand;
        hreg[c][r] = v;
        hn[c][r] = v;
        scr[(m0 + r) * 48 + c * 16 + lc] = f2bf(v);
      }
    __syncthreads();
    { S8U v; v.s = *(const short8*)&scr[srow * 48 + scc];
      __hip_atomic_store(hwp,     v.u[0], __ATOMIC_RELAXED, __HIP_MEMORY_SCOPE_AGENT);
      __hip_atomic_store(hwp + 1, v.u[1], __ATOMIC_RELAXED, __HIP_MEMORY_SCOPE_AGENT); }
    asm volatile("s_waitcnt vmcnt(0)" ::: "memory");
    __syncthreads();
    if (tid == 0) __hip_atomic_fetch_add(ctr, 1, __ATOMIC_RELAXED, __HIP_MEMORY_SCOPE_AGENT);

    // bulk: H[t+1] = hn, R = g (post-arrival, drains in background)
    const size_t hoff = (size_t)(t + 1) * BH;
    #pragma unroll
    for (int c = 0; c < 2; ++c)
      #pragma unroll
      for (int r = 0; r < 4; ++r) {
        H[hoff + (size_t)(m0 + r) * 1024 + jbase + c * 16 + lc] = hn[c][r];
        R[zoff + (size_t)(m0 + r) * 1024 + jbase + c * 16 + lc] = g[c][r];
      }
  }
}

// ---------------- host launcher -------------------------------------------
extern "C" void kernel_launch(void* const* d_in, const int* in_sizes, int n_in,
                              void* d_out, int out_size, void* d_ws, size_t ws_size,
                              hipStream_t stream) {
  (void)in_sizes; (void)n_in; (void)out_size; (void)ws_size;
  const float* x  = (const float*)d_in[0];
  const float* Wz = (const float*)d_in[1];
  const float* bz = (const float*)d_in[2];
  const float* Wh = (const float*)d_in[3];
  const float* bh = (const float*)d_in[4];

  float* H = (float*)d_out;
  float* Z = H + (size_t)(T_STEPS + 1) * BH;
  float* R = Z + (size_t)T_STEPS * BH;

  char* ws = (char*)d_ws;
  int*      ctr   = (int*)ws;                                   // 16 KB region
  u64*      h_buf = (u64*)(ws + 16384);                         // 128 KB
  u64*      ghb   = (u64*)(ws + 16384 + 131072);                // 128 KB
  ushort_t* Wzh   = (ushort_t*)(ws + 16384 + 2 * 131072);       // 2 MB
  ushort_t* Whh   = Wzh + (size_t)HIDDEN * HIDDEN;              // 2 MB
  ushort_t* Wzx   = Whh + (size_t)HIDDEN * HIDDEN;              // 1 MB
  ushort_t* Whx   = Wzx + (size_t)HIDDEN * IDIM;                // 1 MB

  hipFuncSetAttribute((const void*)gru_persist,
                      hipFuncAttributeMaxDynamicSharedMemorySize, 137216);

  hipMemsetAsync(ctr, 0, 16384, stream);
  convert_weights<<<dim3(HIDDEN, 2), 256, 0, stream>>>(Wz, Wh, Wzh, Wzx, Whh, Whx);
  gx_gemm<<<dim3(T_STEPS * BATCH / 64, HIDDEN / 64, 2), 256, 0, stream>>>(
      x, Wzx, Whx, bz, bh, Z, R);
  gru_persist<<<NWGP, 256, 137216, stream>>>(Wzh, Whh, H, Z, R, h_buf, ghb, ctr);
}

// Round 4
// 5160.777 us; speedup vs baseline: 2.2725x; 2.2725x over previous
//
#include <hip/hip_runtime.h>
#include <cstdint>

typedef unsigned short ushort_t;
typedef __attribute__((ext_vector_type(8))) short short8;
typedef __attribute__((ext_vector_type(4))) float f32x4;
typedef unsigned long long u64;

#define T_STEPS 512
#define BATCH   64
#define IDIM    512
#define HIDDEN  1024
#define NWGP    32          // persistent workgroups
#define NC      32          // output columns per WG
#define BH      (BATCH*HIDDEN)   // 65536
#define STW     65536       // ushort index where per-wave staging region begins

__device__ __forceinline__ ushort_t f2bf(float f) {
  unsigned int x = __float_as_uint(f);
  unsigned int r = (x + 0x7fffu + ((x >> 16) & 1u)) >> 16;
  return (ushort_t)r;
}
__device__ __forceinline__ float sigmoid_f(float x) { return 1.f / (1.f + __expf(-x)); }
__device__ __forceinline__ float tanh_f(float x)    { return 1.f - 2.f / (1.f + __expf(2.f * x)); }

// coherent global->LDS direct load, 16B/lane. aux=17 = sc0|sc1 (CPol GLC|SCC):
// bypasses (possibly stale) L1/L2, reads at device scope from LLC.
__device__ __forceinline__ void glds16(const ushort_t* g, ushort_t* l) {
  __builtin_amdgcn_global_load_lds(
      (const __attribute__((address_space(1))) void*)g,
      (__attribute__((address_space(3))) void*)l, 16, 0, 17);
}

// swizzled u64 index into h_buf/ghb: element (gr,k) lives at gr*1024 + (k ^ ((gr&7)<<3))
__device__ __forceinline__ int hswz_u64(int gr, int k0) {   // k0 4-aligned
  return (gr * 1024 + (k0 ^ ((gr & 7) << 3))) >> 2;
}

__device__ __forceinline__ void poll_ctr(int* ctr, int target) {
  if (threadIdx.x == 0) {
    while (__hip_atomic_load(ctr, __ATOMIC_RELAXED, __HIP_MEMORY_SCOPE_AGENT) < target)
      __builtin_amdgcn_s_sleep(1);
  }
  __syncthreads();
}

// ---------------- weight conversion: f32 -> bf16, split h-part / x-part ----
__global__ __launch_bounds__(256) void convert_weights(
    const float* __restrict__ Wz, const float* __restrict__ Wh,
    ushort_t* __restrict__ Wzh, ushort_t* __restrict__ Wzx,
    ushort_t* __restrict__ Whh, ushort_t* __restrict__ Whx)
{
  int j = blockIdx.x;
  const float* W = blockIdx.y ? Wh : Wz;
  ushort_t* Bh = blockIdx.y ? Whh : Wzh;
  ushort_t* Bx = blockIdx.y ? Whx : Wzx;
  const float* row = W + (size_t)j * (HIDDEN + IDIM);
  for (int c = threadIdx.x; c < HIDDEN + IDIM; c += 256) {
    ushort_t v = f2bf(row[c]);
    if (c < HIDDEN) Bh[(size_t)j * HIDDEN + c] = v;
    else            Bx[(size_t)j * IDIM + (c - HIDDEN)] = v;
  }
}

// ---------------- phase 1: Gx = x @ Wx^T + b  (two GEMMs via blockIdx.z) ----
__global__ __launch_bounds__(256) void gx_gemm(
    const float* __restrict__ x,
    const ushort_t* __restrict__ Wzx, const ushort_t* __restrict__ Whx,
    const float* __restrict__ bz, const float* __restrict__ bh,
    float* __restrict__ outZ, float* __restrict__ outR)
{
  const int which = blockIdx.z;
  const ushort_t* W = which ? Whx : Wzx;
  const float* bias = which ? bh : bz;
  float* out = which ? outR : outZ;
  const int m0 = blockIdx.x * 64;
  const int n0 = blockIdx.y * 64;
  __shared__ ushort_t As[64 * 40];
  __shared__ ushort_t Bs[64 * 40];
  const int tid = threadIdx.x;
  const int lane = tid & 63, w4 = tid >> 6;
  const int row = tid >> 2, q = tid & 3;
  f32x4 acc[4] = {{0,0,0,0},{0,0,0,0},{0,0,0,0},{0,0,0,0}};
  for (int kk = 0; kk < IDIM; kk += 32) {
    const float* xs = &x[(size_t)(m0 + row) * IDIM + kk + q * 8];
    float4 f0 = *(const float4*)xs;
    float4 f1 = *(const float4*)(xs + 4);
    short8 av;
    av[0]=f2bf(f0.x); av[1]=f2bf(f0.y); av[2]=f2bf(f0.z); av[3]=f2bf(f0.w);
    av[4]=f2bf(f1.x); av[5]=f2bf(f1.y); av[6]=f2bf(f1.z); av[7]=f2bf(f1.w);
    short8 bv = *(const short8*)&W[(size_t)(n0 + row) * IDIM + kk + q * 8];
    __syncthreads();
    *(short8*)&As[row * 40 + q * 8] = av;
    *(short8*)&Bs[row * 40 + q * 8] = bv;
    __syncthreads();
    short8 af = *(const short8*)&As[(w4 * 16 + (lane & 15)) * 40 + (lane >> 4) * 8];
    #pragma unroll
    for (int c = 0; c < 4; ++c) {
      short8 bf = *(const short8*)&Bs[(c * 16 + (lane & 15)) * 40 + (lane >> 4) * 8];
      acc[c] = __builtin_amdgcn_mfma_f32_16x16x32_bf16(af, bf, acc[c], 0, 0, 0);
    }
  }
  #pragma unroll
  for (int c = 0; c < 4; ++c) {
    int j = n0 + c * 16 + (lane & 15);
    float bv = bias[j];
    #pragma unroll
    for (int r = 0; r < 4; ++r) {
      int m = m0 + w4 * 16 + (lane >> 4) * 4 + r;
      out[(size_t)m * HIDDEN + j] = acc[c][r] + bv;
    }
  }
}

// ---------------- persistent recurrent kernel ------------------------------
// A-operand (h / g*h) flows: sc1 atomic stores (swizzled global layout) ->
// global_load_lds(sc0|sc1) double-buffered K=64 chunks -> ds_read_b128 -> MFMA.
__global__ __launch_bounds__(256) void gru_persist(
    const ushort_t* __restrict__ Wzh, const ushort_t* __restrict__ Whh,
    float* __restrict__ H, float* __restrict__ Z, float* __restrict__ R,
    u64* __restrict__ h_buf, u64* __restrict__ ghb, int* __restrict__ ctr)
{
  extern __shared__ ushort_t smem[];   // [0,32768) Wz slice, [32768,65536) Wh slice,
                                       // [STW, STW+8192) per-wave staging (2KB x 2 bufs x 4 waves)
  const int w = blockIdx.x;
  const int tid = threadIdx.x;
  const int lane = tid & 63, wv = tid >> 6;
  const int jbase = w * NC;
  const int li = lane & 15, q4 = lane >> 4;
  const int R0 = wv * 16;
  const ushort_t* hgu = (const ushort_t*)h_buf;
  const ushort_t* ggu = (const ushort_t*)ghb;

  // stage weight slices (row-XOR swizzle k ^= (row&7)<<3)
  for (int c = tid; c < NC * 128; c += 256) {
    int row = c >> 7, k8 = (c & 127) * 8;
    int dst = row * 1024 + (k8 ^ ((row & 7) << 3));
    *(short8*)&smem[dst]         = *(const short8*)&Wzh[(size_t)(jbase + row) * 1024 + k8];
    *(short8*)&smem[32768 + dst] = *(const short8*)&Whh[(size_t)(jbase + row) * 1024 + k8];
  }

  // init: h0 = 0 in swizzled global image (own 32-col slice, all 64 rows)
  for (int s = tid; s < 512; s += 256) {
    int r = s >> 3, c8 = s & 7;
    __hip_atomic_store(h_buf + hswz_u64(r, jbase + c8 * 4), 0ull,
                       __ATOMIC_RELAXED, __HIP_MEMORY_SCOPE_AGENT);
  }
  asm volatile("s_waitcnt vmcnt(0)" ::: "memory");
  __syncthreads();   // also covers LDS weight staging
  if (tid == 0) __hip_atomic_fetch_add(ctr, 1, __ATOMIC_RELAXED, __HIP_MEMORY_SCOPE_AGENT);
  {  // H[0] = 0 (bulk, post-arrival)
    const int srow = tid >> 2, scc = (tid & 3) * 8;
    float4 z4 = {0.f, 0.f, 0.f, 0.f};
    *(float4*)&H[(size_t)srow * 1024 + jbase + scc]     = z4;
    *(float4*)&H[(size_t)srow * 1024 + jbase + scc + 4] = z4;
  }

  // per-thread constants
  const int asw = (li & 7) << 3;                    // A staged-chunk un-swizzle
  const int wb0 = li * 1024,     wb1 = (16 + li) * 1024;
  const int sz0 = (li & 7) << 3, sz1 = ((16 + li) & 7) << 3;
  const int m0 = wv * 16 + q4 * 4;                  // output batch rows m0..m0+3
  const int sb = STW + wv * 2048;                   // wave staging base (ushort idx)
  const int str0 = lane >> 3, stc = lane & 7;       // broadcast-store mapping
  const int gi0 = hswz_u64(R0 + str0,     jbase + stc * 4);
  const int gi1 = hswz_u64(R0 + 8 + str0, jbase + stc * 4);
  const int scr0 = sb + str0 * 40 + stc * 4;        // scr read addrs (8B aligned)
  const int scr1 = sb + (8 + str0) * 40 + stc * 4;

  float hreg[2][4] = {{0.f,0.f,0.f,0.f},{0.f,0.f,0.f,0.f}};

  for (int t = 0; t < T_STEPS; ++t) {
    const size_t zoff = (size_t)t * BH;

    // ---- phase A: z-gate -------------------------------------------------
    float gz[2][4];
    #pragma unroll
    for (int c = 0; c < 2; ++c)
      #pragma unroll
      for (int r = 0; r < 4; ++r)
        gz[c][r] = Z[zoff + (size_t)(m0 + r) * 1024 + jbase + c * 16 + li];

    poll_ctr(ctr, NWGP * (2 * t + 1));

    f32x4 acc0 = {0,0,0,0}, acc1 = {0,0,0,0};
    {
      const ushort_t* gsrc = hgu + (size_t)(R0 + (lane >> 3)) * 1024 + (lane & 7) * 8;
      glds16(gsrc,             &smem[sb]);
      glds16(gsrc + 8 * 1024,  &smem[sb + 512]);
      glds16(gsrc + 64,            &smem[sb + 1024]);
      glds16(gsrc + 64 + 8 * 1024, &smem[sb + 1536]);
      #pragma unroll
      for (int kc = 0; kc < 16; ++kc) {
        const int kg = kc * 64 + q4 * 8;
        short8 b00 = *(const short8*)&smem[wb0 + (kg ^ sz0)];
        short8 b10 = *(const short8*)&smem[wb1 + (kg ^ sz1)];
        short8 b01 = *(const short8*)&smem[wb0 + ((kg + 32) ^ sz0)];
        short8 b11 = *(const short8*)&smem[wb1 + ((kg + 32) ^ sz1)];
        if (kc < 15) asm volatile("s_waitcnt vmcnt(2)" ::: "memory");
        else         asm volatile("s_waitcnt vmcnt(0)" ::: "memory");
        __builtin_amdgcn_sched_barrier(0);
        const ushort_t* bb = &smem[sb + (kc & 1) * 1024];
        short8 a0 = *(const short8*)&bb[li * 64 + ((q4 * 8) ^ asw)];
        short8 a1 = *(const short8*)&bb[li * 64 + ((32 + q4 * 8) ^ asw)];
        if (kc < 14) {
          const ushort_t* gn = gsrc + (kc + 2) * 64;
          glds16(gn,            &smem[sb + (kc & 1) * 1024]);
          glds16(gn + 8 * 1024, &smem[sb + (kc & 1) * 1024 + 512]);
        }
        acc0 = __builtin_amdgcn_mfma_f32_16x16x32_bf16(a0, b00, acc0, 0, 0, 0);
        acc1 = __builtin_amdgcn_mfma_f32_16x16x32_bf16(a0, b10, acc1, 0, 0, 0);
        acc0 = __builtin_amdgcn_mfma_f32_16x16x32_bf16(a1, b01, acc0, 0, 0, 0);
        acc1 = __builtin_amdgcn_mfma_f32_16x16x32_bf16(a1, b11, acc1, 0, 0, 0);
      }
    }
    float g[2][4];
    #pragma unroll
    for (int c = 0; c < 2; ++c)
      #pragma unroll
      for (int r = 0; r < 4; ++r) {
        g[c][r] = sigmoid_f((c ? acc1[r] : acc0[r]) + gz[c][r]);
        smem[sb + (q4 * 4 + r) * 40 + c * 16 + li] = f2bf(g[c][r] * hreg[c][r]);
      }
    asm volatile("s_waitcnt lgkmcnt(0)" ::: "memory");
    __builtin_amdgcn_sched_barrier(0);
    { u64 v0 = *(const u64*)&smem[scr0];
      u64 v1 = *(const u64*)&smem[scr1];
      __hip_atomic_store(ghb + gi0, v0, __ATOMIC_RELAXED, __HIP_MEMORY_SCOPE_AGENT);
      __hip_atomic_store(ghb + gi1, v1, __ATOMIC_RELAXED, __HIP_MEMORY_SCOPE_AGENT); }
    asm volatile("s_waitcnt vmcnt(0)" ::: "memory");
    __syncthreads();
    if (tid == 0) __hip_atomic_fetch_add(ctr, 1, __ATOMIC_RELAXED, __HIP_MEMORY_SCOPE_AGENT);

    // bulk: Z = g (post-arrival, drains in background)
    #pragma unroll
    for (int c = 0; c < 2; ++c)
      #pragma unroll
      for (int r = 0; r < 4; ++r)
        Z[zoff + (size_t)(m0 + r) * 1024 + jbase + c * 16 + li] = g[c][r];

    // ---- phase B: candidate ---------------------------------------------
    float gh[2][4];
    #pragma unroll
    for (int c = 0; c < 2; ++c)
      #pragma unroll
      for (int r = 0; r < 4; ++r)
        gh[c][r] = R[zoff + (size_t)(m0 + r) * 1024 + jbase + c * 16 + li];

    poll_ctr(ctr, NWGP * (2 * t + 2));

    f32x4 acc2 = {0,0,0,0}, acc3 = {0,0,0,0};
    {
      const ushort_t* gsrc = ggu + (size_t)(R0 + (lane >> 3)) * 1024 + (lane & 7) * 8;
      glds16(gsrc,             &smem[sb]);
      glds16(gsrc + 8 * 1024,  &smem[sb + 512]);
      glds16(gsrc + 64,            &smem[sb + 1024]);
      glds16(gsrc + 64 + 8 * 1024, &smem[sb + 1536]);
      #pragma unroll
      for (int kc = 0; kc < 16; ++kc) {
        const int kg = kc * 64 + q4 * 8;
        short8 b00 = *(const short8*)&smem[32768 + wb0 + (kg ^ sz0)];
        short8 b10 = *(const short8*)&smem[32768 + wb1 + (kg ^ sz1)];
        short8 b01 = *(const short8*)&smem[32768 + wb0 + ((kg + 32) ^ sz0)];
        short8 b11 = *(const short8*)&smem[32768 + wb1 + ((kg + 32) ^ sz1)];
        if (kc < 15) asm volatile("s_waitcnt vmcnt(2)" ::: "memory");
        else         asm volatile("s_waitcnt vmcnt(0)" ::: "memory");
        __builtin_amdgcn_sched_barrier(0);
        const ushort_t* bb = &smem[sb + (kc & 1) * 1024];
        short8 a0 = *(const short8*)&bb[li * 64 + ((q4 * 8) ^ asw)];
        short8 a1 = *(const short8*)&bb[li * 64 + ((32 + q4 * 8) ^ asw)];
        if (kc < 14) {
          const ushort_t* gn = gsrc + (kc + 2) * 64;
          glds16(gn,            &smem[sb + (kc & 1) * 1024]);
          glds16(gn + 8 * 1024, &smem[sb + (kc & 1) * 1024 + 512]);
        }
        acc2 = __builtin_amdgcn_mfma_f32_16x16x32_bf16(a0, b00, acc2, 0, 0, 0);
        acc3 = __builtin_amdgcn_mfma_f32_16x16x32_bf16(a0, b10, acc3, 0, 0, 0);
        acc2 = __builtin_amdgcn_mfma_f32_16x16x32_bf16(a1, b01, acc2, 0, 0, 0);
        acc3 = __builtin_amdgcn_mfma_f32_16x16x32_bf16(a1, b11, acc3, 0, 0, 0);
      }
    }
    float hn[2][4];
    #pragma unroll
    for (int c = 0; c < 2; ++c)
      #pragma unroll
      for (int r = 0; r < 4; ++r) {
        float cand = tanh_f((c ? acc3[r] : acc2[r]) + gh[c][r]);
        float v = (1.f - g[c][r]) * hreg[c][r] + g[c][r] * cand;
        hreg[c][r] = v;
        hn[c][r] = v;
        smem[sb + (q4 * 4 + r) * 40 + c * 16 + li] = f2bf(v);
      }
    asm volatile("s_waitcnt lgkmcnt(0)" ::: "memory");
    __builtin_amdgcn_sched_barrier(0);
    { u64 v0 = *(const u64*)&smem[scr0];
      u64 v1 = *(const u64*)&smem[scr1];
      __hip_atomic_store(h_buf + gi0, v0, __ATOMIC_RELAXED, __HIP_MEMORY_SCOPE_AGENT);
      __hip_atomic_store(h_buf + gi1, v1, __ATOMIC_RELAXED, __HIP_MEMORY_SCOPE_AGENT); }
    asm volatile("s_waitcnt vmcnt(0)" ::: "memory");
    __syncthreads();
    if (tid == 0) __hip_atomic_fetch_add(ctr, 1, __ATOMIC_RELAXED, __HIP_MEMORY_SCOPE_AGENT);

    // bulk: H[t+1] = hn, R = g (post-arrival, drains in background)
    const size_t hoff = (size_t)(t + 1) * BH;
    #pragma unroll
    for (int c = 0; c < 2; ++c)
      #pragma unroll
      for (int r = 0; r < 4; ++r) {
        H[hoff + (size_t)(m0 + r) * 1024 + jbase + c * 16 + li] = hn[c][r];
        R[zoff + (size_t)(m0 + r) * 1024 + jbase + c * 16 + li] = g[c][r];
      }
  }
}

// ---------------- host launcher -------------------------------------------
extern "C" void kernel_launch(void* const* d_in, const int* in_sizes, int n_in,
                              void* d_out, int out_size, void* d_ws, size_t ws_size,
                              hipStream_t stream) {
  (void)in_sizes; (void)n_in; (void)out_size; (void)ws_size;
  const float* x  = (const float*)d_in[0];
  const float* Wz = (const float*)d_in[1];
  const float* bz = (const float*)d_in[2];
  const float* Wh = (const float*)d_in[3];
  const float* bh = (const float*)d_in[4];

  float* H = (float*)d_out;
  float* Z = H + (size_t)(T_STEPS + 1) * BH;
  float* R = Z + (size_t)T_STEPS * BH;

  char* ws = (char*)d_ws;
  int*      ctr   = (int*)ws;                                   // 16 KB region
  u64*      h_buf = (u64*)(ws + 16384);                         // 128 KB (swizzled bf16 image)
  u64*      ghb   = (u64*)(ws + 16384 + 131072);                // 128 KB
  ushort_t* Wzh   = (ushort_t*)(ws + 16384 + 2 * 131072);       // 2 MB
  ushort_t* Whh   = Wzh + (size_t)HIDDEN * HIDDEN;              // 2 MB
  ushort_t* Wzx   = Whh + (size_t)HIDDEN * HIDDEN;              // 1 MB
  ushort_t* Whx   = Wzx + (size_t)HIDDEN * IDIM;                // 1 MB

  hipFuncSetAttribute((const void*)gru_persist,
                      hipFuncAttributeMaxDynamicSharedMemorySize, 147456);

  hipMemsetAsync(ctr, 0, 16384, stream);
  convert_weights<<<dim3(HIDDEN, 2), 256, 0, stream>>>(Wz, Wh, Wzh, Wzx, Whh, Whx);
  gx_gemm<<<dim3(T_STEPS * BATCH / 64, HIDDEN / 64, 2), 256, 0, stream>>>(
      x, Wzx, Whx, bz, bh, Z, R);
  gru_persist<<<NWGP, 256, 147456, stream>>>(Wzh, Whh, H, Z, R, h_buf, ghb, ctr);
}